// Round 2
// baseline (2595.032 us; speedup 1.0000x reference)
//
#include <hip/hip_runtime.h>

#define RG_ITERS 12
#define RG_S 64
#define RG_IN 128
#define RG_H 16
#define RG_OUT 8
#define RG_BN_EPS 1e-5

// ---------------------------------------------------------------------------
// Detect whether edge_index buffer is int64 (odd int32 words all zero) or int32
// ---------------------------------------------------------------------------
__global__ void detect_i64_kernel(const unsigned int* __restrict__ ei32, int* __restrict__ flag) {
    if (blockIdx.x == 0 && threadIdx.x == 0) {
        int allz = 1;
        for (int i = 1; i < 64; i += 2) allz &= (ei32[i] == 0u);
        *flag = allz;  // 1 -> int64, 0 -> int32
    }
}

__device__ __forceinline__ int load_edge(const void* ei, int is64, long long idx) {
    return is64 ? (int)((const long long*)ei)[idx] : ((const int*)ei)[idx];
}

// ---------------------------------------------------------------------------
// CSR build: in-degree count -> exclusive scan -> fill adjacency (src per dst)
// ---------------------------------------------------------------------------
__global__ void deg_kernel(const void* __restrict__ ei, const int* __restrict__ flag,
                           int* __restrict__ deg, int E) {
    int i = blockIdx.x * blockDim.x + threadIdx.x;
    if (i >= E) return;
    int dst = load_edge(ei, *flag, (long long)E + i);
    atomicAdd(&deg[dst], 1);
}

__global__ __launch_bounds__(1024) void scan_kernel(const int* __restrict__ deg,
                                                    int* __restrict__ row_off,
                                                    int* __restrict__ cursor, int n) {
    __shared__ int buf[1024];
    __shared__ int carry;
    int tid = threadIdx.x;
    if (tid == 0) carry = 0;
    __syncthreads();
    for (int base = 0; base < n; base += 1024) {
        int i = base + tid;
        int v = (i < n) ? deg[i] : 0;
        buf[tid] = v;
        __syncthreads();
        for (int off = 1; off < 1024; off <<= 1) {
            int t = (tid >= off) ? buf[tid - off] : 0;
            __syncthreads();
            buf[tid] += t;
            __syncthreads();
        }
        if (i < n) {
            int exc = carry + buf[tid] - v;
            row_off[i] = exc;
            cursor[i] = exc;
        }
        __syncthreads();
        if (tid == 0) carry += buf[1023];
        __syncthreads();
    }
    if (tid == 0) row_off[n] = carry;
}

__global__ void fill_kernel(const void* __restrict__ ei, const int* __restrict__ flag,
                            int* __restrict__ cursor, int* __restrict__ adj, int E) {
    int i = blockIdx.x * blockDim.x + threadIdx.x;
    if (i >= E) return;
    int is64 = *flag;
    int src = load_edge(ei, is64, i);
    int dst = load_edge(ei, is64, (long long)E + i);
    int p = atomicAdd(&cursor[dst], 1);
    adj[p] = src;  // row order nondeterministic; counting is order-invariant
}

// ---------------------------------------------------------------------------
// Input layer: state0[n] = argmax_j ( x[n,:] @ W_in[:,j] + b_in[j] )
// one wave per node, lane j owns logit j; f64 accumulate -> exact argmax
// ---------------------------------------------------------------------------
__global__ __launch_bounds__(256) void input_kernel(const float* __restrict__ x,
                                                    const float* __restrict__ W_in,
                                                    const float* __restrict__ b_in,
                                                    unsigned char* __restrict__ st, int n) {
    int lane = threadIdx.x & 63;
    int wid = threadIdx.x >> 6;
    int node = blockIdx.x * 4 + wid;
    if (node >= n) node = n - 1;  // duplicate work, same deterministic value
    const float* xr = x + (size_t)node * RG_IN;
    double acc = (double)b_in[lane];
#pragma unroll 8
    for (int k = 0; k < RG_IN; ++k)
        acc += (double)xr[k] * (double)W_in[k * RG_S + lane];
    // argmax across 64 lanes, tie -> smallest index (matches jnp.argmax)
    double best = acc;
    int bi = lane;
#pragma unroll
    for (int off = 32; off; off >>= 1) {
        double ov = __shfl_xor(best, off);
        int oi = __shfl_xor(bi, off);
        if (ov > best || (ov == best && oi < bi)) { best = ov; bi = oi; }
    }
    if (lane == 0) st[node] = (unsigned char)bi;
}

// ---------------------------------------------------------------------------
// One recurrent iteration — REGISTER-ONLY (no LDS, no atomics):
//   lane j accumulates cnt_j = #in-neighbors with state j via shfl broadcast
//   z_j = b_rec[j] + W_rec[64+st_old][j] + sum_k min(cnt_k,10) * W_rec[k][j]
//   st_new = argmax_j bn(z)
// ---------------------------------------------------------------------------
__global__ __launch_bounds__(256) void iter_kernel(const int* __restrict__ row_off,
                                                   const int* __restrict__ adj,
                                                   const unsigned char* __restrict__ st_in,
                                                   unsigned char* __restrict__ st_out,
                                                   const float* __restrict__ W_rec,
                                                   const float* __restrict__ b_rec,
                                                   const float* __restrict__ bn_g,
                                                   const float* __restrict__ bn_b,
                                                   const float* __restrict__ bn_m,
                                                   const float* __restrict__ bn_v, int n) {
    int lane = threadIdx.x & 63;
    int wid = threadIdx.x >> 6;
    int node = blockIdx.x * 4 + wid;
    if (node >= n) node = n - 1;

    int beg = row_off[node], end = row_off[node + 1];
    int cnt = 0;  // exact count of in-neighbors whose state == lane
    for (int base = beg; base < end; base += 64) {
        int idx = base + lane;
        int sv = (idx < end) ? (int)st_in[adj[idx]] : -1;
#pragma unroll 16
        for (int t = 0; t < 64; ++t) {
            int s_t = __shfl(sv, t);          // broadcast lane t's neighbor state
            cnt += (s_t == lane) ? 1 : 0;     // -1 (invalid) never matches
        }
    }

    int st_old = (int)st_in[node];
    double z = (double)b_rec[lane] + (double)W_rec[(RG_S + st_old) * RG_S + lane];
#pragma unroll 8
    for (int k = 0; k < RG_S; ++k) {
        int ck = __shfl(cnt, k);              // channel-k count from lane k
        double ak = (ck > 10) ? 10.0 : (double)ck;
        z += ak * (double)W_rec[k * RG_S + lane];  // +0*W exact no-op for empty bins
    }

    double y = (z - (double)bn_m[lane]) *
                   ((double)bn_g[lane] / sqrt((double)bn_v[lane] + RG_BN_EPS)) +
               (double)bn_b[lane];

    double best = y;
    int bi = lane;
#pragma unroll
    for (int off = 32; off; off >>= 1) {
        double ov = __shfl_xor(best, off);
        int oi = __shfl_xor(bi, off);
        if (ov > best || (ov == best && oi < bi)) { best = ov; bi = oi; }
    }
    if (lane == 0) st_out[node] = (unsigned char)bi;
}

// ---------------------------------------------------------------------------
// Output MLP collapses to a 64x8 lookup table over the final state
// ---------------------------------------------------------------------------
__global__ void table_kernel(const float* __restrict__ Wo1, const float* __restrict__ bo1,
                             const float* __restrict__ g, const float* __restrict__ b,
                             const float* __restrict__ m, const float* __restrict__ v,
                             const float* __restrict__ Wo2, const float* __restrict__ bo2,
                             float* __restrict__ table) {
    int k = threadIdx.x;
    if (k >= RG_S) return;
    double h[RG_H];
#pragma unroll
    for (int j = 0; j < RG_H; ++j) {
        double z = (double)Wo1[k * RG_H + j] + (double)bo1[j];
        double y = (z - (double)m[j]) * ((double)g[j] / sqrt((double)v[j] + RG_BN_EPS)) +
                   (double)b[j];
        h[j] = y > 0.0 ? y : 0.0;
    }
#pragma unroll
    for (int o = 0; o < RG_OUT; ++o) {
        double acc = (double)bo2[o];
#pragma unroll
        for (int j = 0; j < RG_H; ++j) acc += h[j] * (double)Wo2[j * RG_OUT + o];
        table[k * RG_OUT + o] = (float)acc;
    }
}

__global__ void out_kernel(const unsigned char* __restrict__ st, const float* __restrict__ table,
                           float* __restrict__ out, int n) {
    int i = blockIdx.x * blockDim.x + threadIdx.x;
    if (i >= n) return;
    int s = (int)st[i];
    float4 a = ((const float4*)table)[s * 2];
    float4 b = ((const float4*)table)[s * 2 + 1];
    ((float4*)out)[(size_t)i * 2] = a;
    ((float4*)out)[(size_t)i * 2 + 1] = b;
}

// ---------------------------------------------------------------------------
extern "C" void kernel_launch(void* const* d_in, const int* in_sizes, int n_in,
                              void* d_out, int out_size, void* d_ws, size_t ws_size,
                              hipStream_t stream) {
    const float* x     = (const float*)d_in[0];
    const void*  ei    = d_in[1];
    const float* W_in  = (const float*)d_in[2];
    const float* b_in  = (const float*)d_in[3];
    const float* W_rec = (const float*)d_in[4];
    const float* b_rec = (const float*)d_in[5];
    const float* bn_g  = (const float*)d_in[6];
    const float* bn_b  = (const float*)d_in[7];
    const float* bn_m  = (const float*)d_in[8];
    const float* bn_v  = (const float*)d_in[9];
    const float* Wo1   = (const float*)d_in[10];
    const float* bo1   = (const float*)d_in[11];
    const float* bno_g = (const float*)d_in[12];
    const float* bno_b = (const float*)d_in[13];
    const float* bno_m = (const float*)d_in[14];
    const float* bno_v = (const float*)d_in[15];
    const float* Wo2   = (const float*)d_in[16];
    const float* bo2   = (const float*)d_in[17];

    int N = in_sizes[0] / RG_IN;
    int E = in_sizes[1] / 2;

    char* ws = (char*)d_ws;
    size_t off = 0;
    auto alloc = [&](size_t bytes) -> void* {
        void* p = ws + off;
        off = (off + bytes + 255) & ~(size_t)255;
        return p;
    };
    int*           flag    = (int*)alloc(sizeof(int));
    int*           deg     = (int*)alloc((size_t)N * sizeof(int));
    int*           row_off = (int*)alloc((size_t)(N + 1) * sizeof(int));
    int*           cursor  = (int*)alloc((size_t)N * sizeof(int));
    int*           adj     = (int*)alloc((size_t)E * sizeof(int));
    unsigned char* stA     = (unsigned char*)alloc((size_t)N);
    unsigned char* stB     = (unsigned char*)alloc((size_t)N);
    float*         table   = (float*)alloc(RG_S * RG_OUT * sizeof(float));

    hipMemsetAsync(deg, 0, (size_t)N * sizeof(int), stream);
    detect_i64_kernel<<<1, 64, 0, stream>>>((const unsigned int*)ei, flag);

    int eb = (E + 255) / 256;
    deg_kernel<<<eb, 256, 0, stream>>>(ei, flag, deg, E);
    scan_kernel<<<1, 1024, 0, stream>>>(deg, row_off, cursor, N);
    fill_kernel<<<eb, 256, 0, stream>>>(ei, flag, cursor, adj, E);

    int nb4 = (N + 3) / 4;
    input_kernel<<<nb4, 256, 0, stream>>>(x, W_in, b_in, stA, N);

    unsigned char* sin = stA;
    unsigned char* sout = stB;
    for (int it = 0; it < RG_ITERS; ++it) {
        iter_kernel<<<nb4, 256, 0, stream>>>(row_off, adj, sin, sout, W_rec, b_rec, bn_g, bn_b,
                                             bn_m, bn_v, N);
        unsigned char* t = sin; sin = sout; sout = t;
    }

    table_kernel<<<1, 64, 0, stream>>>(Wo1, bo1, bno_g, bno_b, bno_m, bno_v, Wo2, bo2, table);
    out_kernel<<<(N + 255) / 256, 256, 0, stream>>>(sin, table, (float*)d_out, N);
}

// Round 3
// 1838.232 us; speedup vs baseline: 1.4117x; 1.4117x over previous
//
#include <hip/hip_runtime.h>

#define RG_ITERS 12
#define RG_S 64
#define RG_IN 128
#define RG_H 16
#define RG_OUT 8
#define RG_BN_EPS 1e-5

// ---------------------------------------------------------------------------
// Detect whether edge_index buffer is int64 (odd int32 words all zero) or int32
// ---------------------------------------------------------------------------
__global__ void detect_i64_kernel(const unsigned int* __restrict__ ei32, int* __restrict__ flag) {
    if (blockIdx.x == 0 && threadIdx.x == 0) {
        int allz = 1;
        for (int i = 1; i < 64; i += 2) allz &= (ei32[i] == 0u);
        *flag = allz;  // 1 -> int64, 0 -> int32
    }
}

__device__ __forceinline__ int load_edge(const void* ei, int is64, long long idx) {
    return is64 ? (int)((const long long*)ei)[idx] : ((const int*)ei)[idx];
}

// ---------------------------------------------------------------------------
// CSR build: in-degree count -> two-level exclusive scan -> fill adjacency
// ---------------------------------------------------------------------------
__global__ void deg_kernel(const void* __restrict__ ei, const int* __restrict__ flag,
                           int* __restrict__ deg, int E) {
    int i = blockIdx.x * blockDim.x + threadIdx.x;
    if (i >= E) return;
    int dst = load_edge(ei, *flag, (long long)E + i);
    atomicAdd(&deg[dst], 1);
}

// per-256-chunk sums
__global__ __launch_bounds__(256) void scanA_kernel(const int* __restrict__ deg,
                                                    int* __restrict__ bsum, int n) {
    int i = blockIdx.x * 256 + threadIdx.x;
    int v = (i < n) ? deg[i] : 0;
#pragma unroll
    for (int off = 32; off; off >>= 1) v += __shfl_xor(v, off);
    __shared__ int ws[4];
    if ((threadIdx.x & 63) == 0) ws[threadIdx.x >> 6] = v;
    __syncthreads();
    if (threadIdx.x == 0) bsum[blockIdx.x] = ws[0] + ws[1] + ws[2] + ws[3];
}

// exclusive scan of block sums (nb <= a few thousand), single block w/ carry loop
__global__ __launch_bounds__(512) void scanB_kernel(int* __restrict__ bsum,
                                                    int* __restrict__ row_off, int nb, int n) {
    __shared__ int buf[512];
    __shared__ int carry;
    int tid = threadIdx.x;
    if (tid == 0) carry = 0;
    __syncthreads();
    for (int base = 0; base < nb; base += 512) {
        int i = base + tid;
        int v = (i < nb) ? bsum[i] : 0;
        buf[tid] = v;
        __syncthreads();
        for (int off = 1; off < 512; off <<= 1) {
            int t = (tid >= off) ? buf[tid - off] : 0;
            __syncthreads();
            buf[tid] += t;
            __syncthreads();
        }
        if (i < nb) bsum[i] = carry + buf[tid] - v;  // exclusive
        __syncthreads();
        if (tid == 0) carry += buf[511];
        __syncthreads();
    }
    if (tid == 0) row_off[n] = carry;  // total edge count
}

// re-scan each 256-chunk, add block offset, emit row_off + cursor
__global__ __launch_bounds__(256) void scanC_kernel(const int* __restrict__ deg,
                                                    const int* __restrict__ bsum,
                                                    int* __restrict__ row_off,
                                                    int* __restrict__ cursor, int n) {
    __shared__ int buf[256];
    int tid = threadIdx.x;
    int i = blockIdx.x * 256 + tid;
    int v = (i < n) ? deg[i] : 0;
    buf[tid] = v;
    __syncthreads();
    for (int off = 1; off < 256; off <<= 1) {
        int t = (tid >= off) ? buf[tid - off] : 0;
        __syncthreads();
        buf[tid] += t;
        __syncthreads();
    }
    if (i < n) {
        int e = bsum[blockIdx.x] + buf[tid] - v;
        row_off[i] = e;
        cursor[i] = e;
    }
}

__global__ void fill_kernel(const void* __restrict__ ei, const int* __restrict__ flag,
                            int* __restrict__ cursor, int* __restrict__ adj, int E) {
    int i = blockIdx.x * blockDim.x + threadIdx.x;
    if (i >= E) return;
    int is64 = *flag;
    int src = load_edge(ei, is64, i);
    int dst = load_edge(ei, is64, (long long)E + i);
    int p = atomicAdd(&cursor[dst], 1);
    adj[p] = src;  // row order nondeterministic; counting is order-invariant
}

// ---------------------------------------------------------------------------
// Input layer: state0[n] = argmax_j ( x[n,:] @ W_in[:,j] + b_in[j] )
// W_in staged in LDS; grid-stride; lane j owns logit j; f64 -> exact argmax
// ---------------------------------------------------------------------------
__global__ __launch_bounds__(256) void input_kernel(const float* __restrict__ x,
                                                    const float* __restrict__ W_in,
                                                    const float* __restrict__ b_in,
                                                    unsigned char* __restrict__ st, int n) {
    __shared__ float wsh[RG_IN * RG_S];  // 32 KB
    for (int i = threadIdx.x; i < RG_IN * RG_S; i += 256) wsh[i] = W_in[i];
    __syncthreads();
    int lane = threadIdx.x & 63;
    int wid = threadIdx.x >> 6;
    double bini = (double)b_in[lane];
    int stride = gridDim.x * 4;
    for (int node = blockIdx.x * 4 + wid; node < n; node += stride) {
        const float* xr = x + (size_t)node * RG_IN;
        double acc = bini;
#pragma unroll 8
        for (int k = 0; k < RG_IN; ++k)
            acc += (double)xr[k] * (double)wsh[k * RG_S + lane];
        double best = acc;
        int bi = lane;
#pragma unroll
        for (int off = 32; off; off >>= 1) {
            double ov = __shfl_xor(best, off);
            int oi = __shfl_xor(bi, off);
            if (ov > best || (ov == best && oi < bi)) { best = ov; bi = oi; }
        }
        if (lane == 0) st[node] = (unsigned char)bi;
    }
}

// ---------------------------------------------------------------------------
// One recurrent iteration — register-only, ballot histogram, nibble-packed
// counts, W_rec column held in registers across a grid-stride node loop.
//   cnt_j = #in-neighbors with state j  (6-ballot match + popc)
//   z_j   = b_rec[j] + W_rec[64+st_old][j] + sum_k min(cnt_k,10)*W_rec[k][j]
//   st_new = argmax_j bn(z)   (f64 exact)
// ---------------------------------------------------------------------------
__global__ __launch_bounds__(256) void iter_kernel(const int* __restrict__ row_off,
                                                   const int* __restrict__ adj,
                                                   const unsigned char* __restrict__ st_in,
                                                   unsigned char* __restrict__ st_out,
                                                   const float* __restrict__ W_rec,
                                                   const float* __restrict__ b_rec,
                                                   const float* __restrict__ bn_g,
                                                   const float* __restrict__ bn_b,
                                                   const float* __restrict__ bn_m,
                                                   const float* __restrict__ bn_v, int n) {
    int lane = threadIdx.x & 63;
    int wid = threadIdx.x >> 6;

    float wcol[RG_S];  // column `lane` of W_rec first half, statically indexed
#pragma unroll
    for (int k = 0; k < RG_S; ++k) wcol[k] = W_rec[k * RG_S + lane];
    double brec = (double)b_rec[lane];
    double bnm = (double)bn_m[lane];
    double bns = (double)bn_g[lane] / sqrt((double)bn_v[lane] + RG_BN_EPS);
    double bnb = (double)bn_b[lane];

    int stride = gridDim.x * 4;
    for (int node = blockIdx.x * 4 + wid; node < n; node += stride) {
        int beg = row_off[node], end = row_off[node + 1];
        int cnt = 0;  // exact count of in-neighbors with state == lane
        for (int base = beg; base < end; base += 64) {
            int idx = base + lane;
            unsigned long long valid = __ballot(idx < end);
            int sv = (idx < end) ? (int)st_in[adj[idx]] : 0;
            unsigned long long mm = valid;
#pragma unroll
            for (int b = 0; b < 6; ++b) {
                unsigned long long bl = __ballot(((sv >> b) & 1) != 0);
                mm &= ((lane >> b) & 1) ? bl : ~bl;
            }
            cnt += (int)__popcll(mm);
        }
        // clamp to 10 (fits a nibble), butterfly-pack all 64 counts into pk[8]
        unsigned v = (cnt > 10) ? 10u : (unsigned)cnt;
        unsigned p;
        p = __shfl_xor(v, 1);  v = (lane & 1) ? (p | (v << 4))  : (v | (p << 4));
        p = __shfl_xor(v, 2);  v = (lane & 2) ? (p | (v << 8))  : (v | (p << 8));
        p = __shfl_xor(v, 4);  v = (lane & 4) ? (p | (v << 16)) : (v | (p << 16));
        unsigned q0, q1;
        p = __shfl_xor(v, 8);
        q0 = (lane & 8) ? p : v;  q1 = (lane & 8) ? v : p;
        unsigned r0 = __shfl_xor(q0, 16), r1 = __shfl_xor(q1, 16);
        unsigned s0, s1, s2, s3;
        if (lane & 16) { s0 = r0; s1 = r1; s2 = q0; s3 = q1; }
        else           { s0 = q0; s1 = q1; s2 = r0; s3 = r1; }
        unsigned t0 = __shfl_xor(s0, 32), t1 = __shfl_xor(s1, 32),
                 t2 = __shfl_xor(s2, 32), t3 = __shfl_xor(s3, 32);
        unsigned pk[8];
        if (lane & 32) { pk[0]=t0; pk[1]=t1; pk[2]=t2; pk[3]=t3; pk[4]=s0; pk[5]=s1; pk[6]=s2; pk[7]=s3; }
        else           { pk[0]=s0; pk[1]=s1; pk[2]=s2; pk[3]=s3; pk[4]=t0; pk[5]=t1; pk[6]=t2; pk[7]=t3; }

        int st_old = (int)st_in[node];
        double z = brec + (double)W_rec[(RG_S + st_old) * RG_S + lane];
#pragma unroll
        for (int k = 0; k < RG_S; ++k) {
            unsigned a = (pk[k >> 3] >> ((k & 7) * 4)) & 0xFu;  // all-static indexing
            z += (double)a * (double)wcol[k];                    // exact: int<=10 * f32 in f64
        }
        double y = (z - bnm) * bns + bnb;

        double best = y;
        int bi = lane;
#pragma unroll
        for (int off = 32; off; off >>= 1) {
            double ov = __shfl_xor(best, off);
            int oi = __shfl_xor(bi, off);
            if (ov > best || (ov == best && oi < bi)) { best = ov; bi = oi; }
        }
        if (lane == 0) st_out[node] = (unsigned char)bi;
    }
}

// ---------------------------------------------------------------------------
// Output MLP collapses to a 64x8 lookup table over the final state
// ---------------------------------------------------------------------------
__global__ void table_kernel(const float* __restrict__ Wo1, const float* __restrict__ bo1,
                             const float* __restrict__ g, const float* __restrict__ b,
                             const float* __restrict__ m, const float* __restrict__ v,
                             const float* __restrict__ Wo2, const float* __restrict__ bo2,
                             float* __restrict__ table) {
    int k = threadIdx.x;
    if (k >= RG_S) return;
    double h[RG_H];
#pragma unroll
    for (int j = 0; j < RG_H; ++j) {
        double z = (double)Wo1[k * RG_H + j] + (double)bo1[j];
        double y = (z - (double)m[j]) * ((double)g[j] / sqrt((double)v[j] + RG_BN_EPS)) +
                   (double)b[j];
        h[j] = y > 0.0 ? y : 0.0;
    }
#pragma unroll
    for (int o = 0; o < RG_OUT; ++o) {
        double acc = (double)bo2[o];
#pragma unroll
        for (int j = 0; j < RG_H; ++j) acc += h[j] * (double)Wo2[j * RG_OUT + o];
        table[k * RG_OUT + o] = (float)acc;
    }
}

__global__ void out_kernel(const unsigned char* __restrict__ st, const float* __restrict__ table,
                           float* __restrict__ out, int n) {
    int i = blockIdx.x * blockDim.x + threadIdx.x;
    if (i >= n) return;
    int s = (int)st[i];
    float4 a = ((const float4*)table)[s * 2];
    float4 b = ((const float4*)table)[s * 2 + 1];
    ((float4*)out)[(size_t)i * 2] = a;
    ((float4*)out)[(size_t)i * 2 + 1] = b;
}

// ---------------------------------------------------------------------------
extern "C" void kernel_launch(void* const* d_in, const int* in_sizes, int n_in,
                              void* d_out, int out_size, void* d_ws, size_t ws_size,
                              hipStream_t stream) {
    const float* x     = (const float*)d_in[0];
    const void*  ei    = d_in[1];
    const float* W_in  = (const float*)d_in[2];
    const float* b_in  = (const float*)d_in[3];
    const float* W_rec = (const float*)d_in[4];
    const float* b_rec = (const float*)d_in[5];
    const float* bn_g  = (const float*)d_in[6];
    const float* bn_b  = (const float*)d_in[7];
    const float* bn_m  = (const float*)d_in[8];
    const float* bn_v  = (const float*)d_in[9];
    const float* Wo1   = (const float*)d_in[10];
    const float* bo1   = (const float*)d_in[11];
    const float* bno_g = (const float*)d_in[12];
    const float* bno_b = (const float*)d_in[13];
    const float* bno_m = (const float*)d_in[14];
    const float* bno_v = (const float*)d_in[15];
    const float* Wo2   = (const float*)d_in[16];
    const float* bo2   = (const float*)d_in[17];

    int N = in_sizes[0] / RG_IN;
    int E = in_sizes[1] / 2;

    char* ws = (char*)d_ws;
    size_t off = 0;
    auto alloc = [&](size_t bytes) -> void* {
        void* p = ws + off;
        off = (off + bytes + 255) & ~(size_t)255;
        return p;
    };
    int nchunks = (N + 255) / 256;
    int*           flag    = (int*)alloc(sizeof(int));
    int*           deg     = (int*)alloc((size_t)N * sizeof(int));
    int*           row_off = (int*)alloc((size_t)(N + 1) * sizeof(int));
    int*           cursor  = (int*)alloc((size_t)N * sizeof(int));
    int*           adj     = (int*)alloc((size_t)E * sizeof(int));
    int*           bsum    = (int*)alloc((size_t)nchunks * sizeof(int));
    unsigned char* stA     = (unsigned char*)alloc((size_t)N);
    unsigned char* stB     = (unsigned char*)alloc((size_t)N);
    float*         table   = (float*)alloc(RG_S * RG_OUT * sizeof(float));

    hipMemsetAsync(deg, 0, (size_t)N * sizeof(int), stream);
    detect_i64_kernel<<<1, 64, 0, stream>>>((const unsigned int*)ei, flag);

    int eb = (E + 255) / 256;
    deg_kernel<<<eb, 256, 0, stream>>>(ei, flag, deg, E);
    scanA_kernel<<<nchunks, 256, 0, stream>>>(deg, bsum, N);
    scanB_kernel<<<1, 512, 0, stream>>>(bsum, row_off, nchunks, N);
    scanC_kernel<<<nchunks, 256, 0, stream>>>(deg, bsum, row_off, cursor, N);
    fill_kernel<<<eb, 256, 0, stream>>>(ei, flag, cursor, adj, E);

    input_kernel<<<512, 256, 0, stream>>>(x, W_in, b_in, stA, N);

    unsigned char* sin = stA;
    unsigned char* sout = stB;
    for (int it = 0; it < RG_ITERS; ++it) {
        iter_kernel<<<1024, 256, 0, stream>>>(row_off, adj, sin, sout, W_rec, b_rec, bn_g, bn_b,
                                              bn_m, bn_v, N);
        unsigned char* t = sin; sin = sout; sout = t;
    }

    table_kernel<<<1, 64, 0, stream>>>(Wo1, bo1, bno_g, bno_b, bno_m, bno_v, Wo2, bo2, table);
    out_kernel<<<(N + 255) / 256, 256, 0, stream>>>(sin, table, (float*)d_out, N);
}

// Round 4
// 1649.323 us; speedup vs baseline: 1.5734x; 1.1145x over previous
//
#include <hip/hip_runtime.h>

#define RG_ITERS 12
#define RG_S 64
#define RG_IN 128
#define RG_H 16
#define RG_OUT 8
#define RG_BN_EPS 1e-5

// ---------------------------------------------------------------------------
// Detect whether edge_index buffer is int64 (odd int32 words all zero) or int32
// ---------------------------------------------------------------------------
__global__ void detect_i64_kernel(const unsigned int* __restrict__ ei32, int* __restrict__ flag) {
    if (blockIdx.x == 0 && threadIdx.x == 0) {
        int allz = 1;
        for (int i = 1; i < 64; i += 2) allz &= (ei32[i] == 0u);
        *flag = allz;  // 1 -> int64, 0 -> int32
    }
}

__device__ __forceinline__ int load_edge(const void* ei, int is64, long long idx) {
    return is64 ? (int)((const long long*)ei)[idx] : ((const int*)ei)[idx];
}

// Compact edge list to int32 src/dst streams (handles i64 or i32 input)
__global__ void compact_kernel(const void* __restrict__ ei, const int* __restrict__ flag,
                               int* __restrict__ srcs, int* __restrict__ dsts, int E) {
    int is64 = *flag;
    int stride = gridDim.x * blockDim.x;
    for (int i = blockIdx.x * blockDim.x + threadIdx.x; i < E; i += stride) {
        srcs[i] = load_edge(ei, is64, i);
        dsts[i] = load_edge(ei, is64, (long long)E + i);
    }
}

// ---------------------------------------------------------------------------
// CSR build, L2-windowed: class r = blockIdx&7 (round-robin -> XCD r) owns
// dst range [r*span, (r+1)*span). Scatter targets stay in that XCD's L2.
// ---------------------------------------------------------------------------
__global__ __launch_bounds__(256) void deg2_kernel(const int* __restrict__ dsts,
                                                   int* __restrict__ deg, int E, int N) {
    int r = blockIdx.x & 7;
    int nb = gridDim.x >> 3;
    int bi = blockIdx.x >> 3;
    int span = (N + 7) >> 3;
    int lo = r * span;
    int hi = lo + span; hi = hi < N ? hi : N;
    int stride = nb * 256;
    for (int i = bi * 256 + threadIdx.x; i < E; i += stride) {
        int d = dsts[i];
        if (d >= lo && d < hi) atomicAdd(&deg[d], 1);
    }
}

__global__ __launch_bounds__(256) void fill2_kernel(const int* __restrict__ srcs,
                                                    const int* __restrict__ dsts,
                                                    int* __restrict__ cursor,
                                                    int* __restrict__ adj, int E, int N) {
    int r = blockIdx.x & 7;
    int nb = gridDim.x >> 3;
    int bi = blockIdx.x >> 3;
    int span = (N + 7) >> 3;
    int lo = r * span;
    int hi = lo + span; hi = hi < N ? hi : N;
    int stride = nb * 256;
    for (int i = bi * 256 + threadIdx.x; i < E; i += stride) {
        int d = dsts[i];
        if (d >= lo && d < hi) {
            int p = atomicAdd(&cursor[d], 1);
            adj[p] = srcs[i];  // row order nondeterministic; counting is order-invariant
        }
    }
}

// per-256-chunk sums
__global__ __launch_bounds__(256) void scanA_kernel(const int* __restrict__ deg,
                                                    int* __restrict__ bsum, int n) {
    int i = blockIdx.x * 256 + threadIdx.x;
    int v = (i < n) ? deg[i] : 0;
#pragma unroll
    for (int off = 32; off; off >>= 1) v += __shfl_xor(v, off);
    __shared__ int ws[4];
    if ((threadIdx.x & 63) == 0) ws[threadIdx.x >> 6] = v;
    __syncthreads();
    if (threadIdx.x == 0) bsum[blockIdx.x] = ws[0] + ws[1] + ws[2] + ws[3];
}

// exclusive scan of block sums, single block w/ carry loop
__global__ __launch_bounds__(512) void scanB_kernel(int* __restrict__ bsum,
                                                    int* __restrict__ row_off, int nb, int n) {
    __shared__ int buf[512];
    __shared__ int carry;
    int tid = threadIdx.x;
    if (tid == 0) carry = 0;
    __syncthreads();
    for (int base = 0; base < nb; base += 512) {
        int i = base + tid;
        int v = (i < nb) ? bsum[i] : 0;
        buf[tid] = v;
        __syncthreads();
        for (int off = 1; off < 512; off <<= 1) {
            int t = (tid >= off) ? buf[tid - off] : 0;
            __syncthreads();
            buf[tid] += t;
            __syncthreads();
        }
        if (i < nb) bsum[i] = carry + buf[tid] - v;  // exclusive
        __syncthreads();
        if (tid == 0) carry += buf[511];
        __syncthreads();
    }
    if (tid == 0) row_off[n] = carry;  // total edge count
}

// re-scan each 256-chunk, add block offset, emit row_off + cursor
__global__ __launch_bounds__(256) void scanC_kernel(const int* __restrict__ deg,
                                                    const int* __restrict__ bsum,
                                                    int* __restrict__ row_off,
                                                    int* __restrict__ cursor, int n) {
    __shared__ int buf[256];
    int tid = threadIdx.x;
    int i = blockIdx.x * 256 + tid;
    int v = (i < n) ? deg[i] : 0;
    buf[tid] = v;
    __syncthreads();
    for (int off = 1; off < 256; off <<= 1) {
        int t = (tid >= off) ? buf[tid - off] : 0;
        __syncthreads();
        buf[tid] += t;
        __syncthreads();
    }
    if (i < n) {
        int e = bsum[blockIdx.x] + buf[tid] - v;
        row_off[i] = e;
        cursor[i] = e;
    }
}

// ---------------------------------------------------------------------------
// Input layer: state0[n] = argmax_j ( x[n,:] @ W_in[:,j] + b_in[j] )
// float4 x loads, 4 independent f64 accumulators, W_in in LDS; exact argmax
// ---------------------------------------------------------------------------
__global__ __launch_bounds__(256) void input_kernel(const float* __restrict__ x,
                                                    const float* __restrict__ W_in,
                                                    const float* __restrict__ b_in,
                                                    unsigned char* __restrict__ st, int n) {
    __shared__ float wsh[RG_IN * RG_S];  // 32 KB
    for (int i = threadIdx.x; i < RG_IN * RG_S; i += 256) wsh[i] = W_in[i];
    __syncthreads();
    int lane = threadIdx.x & 63;
    int wid = threadIdx.x >> 6;
    double bini = (double)b_in[lane];
    int stride = gridDim.x * 4;
    for (int node = blockIdx.x * 4 + wid; node < n; node += stride) {
        const float4* xr = (const float4*)(x + (size_t)node * RG_IN);
        double a0 = 0.0, a1 = 0.0, a2 = 0.0, a3 = 0.0;
#pragma unroll 8
        for (int k4 = 0; k4 < RG_IN / 4; ++k4) {
            float4 xv = xr[k4];
            int k = k4 * 4;
            a0 += (double)xv.x * (double)wsh[(k + 0) * RG_S + lane];
            a1 += (double)xv.y * (double)wsh[(k + 1) * RG_S + lane];
            a2 += (double)xv.z * (double)wsh[(k + 2) * RG_S + lane];
            a3 += (double)xv.w * (double)wsh[(k + 3) * RG_S + lane];
        }
        double acc = bini + ((a0 + a2) + (a1 + a3));
        double best = acc;
        int bi = lane;
#pragma unroll
        for (int off = 32; off; off >>= 1) {
            double ov = __shfl_xor(best, off);
            int oi = __shfl_xor(bi, off);
            if (ov > best || (ov == best && oi < bi)) { best = ov; bi = oi; }
        }
        if (lane == 0) st[node] = (unsigned char)bi;
    }
}

// ---------------------------------------------------------------------------
// One recurrent iteration — register-only, ballot histogram, nibble-packed
// counts, W_rec column held in registers across a grid-stride node loop.
// ---------------------------------------------------------------------------
__global__ __launch_bounds__(256) void iter_kernel(const int* __restrict__ row_off,
                                                   const int* __restrict__ adj,
                                                   const unsigned char* __restrict__ st_in,
                                                   unsigned char* __restrict__ st_out,
                                                   const float* __restrict__ W_rec,
                                                   const float* __restrict__ b_rec,
                                                   const float* __restrict__ bn_g,
                                                   const float* __restrict__ bn_b,
                                                   const float* __restrict__ bn_m,
                                                   const float* __restrict__ bn_v, int n) {
    int lane = threadIdx.x & 63;
    int wid = threadIdx.x >> 6;

    float wcol[RG_S];  // column `lane` of W_rec first half, statically indexed
#pragma unroll
    for (int k = 0; k < RG_S; ++k) wcol[k] = W_rec[k * RG_S + lane];
    double brec = (double)b_rec[lane];
    double bnm = (double)bn_m[lane];
    double bns = (double)bn_g[lane] / sqrt((double)bn_v[lane] + RG_BN_EPS);
    double bnb = (double)bn_b[lane];

    int stride = gridDim.x * 4;
    for (int node = blockIdx.x * 4 + wid; node < n; node += stride) {
        int beg = row_off[node], end = row_off[node + 1];
        int cnt = 0;  // exact count of in-neighbors with state == lane
        for (int base = beg; base < end; base += 64) {
            int idx = base + lane;
            unsigned long long valid = __ballot(idx < end);
            int sv = (idx < end) ? (int)st_in[adj[idx]] : 0;
            unsigned long long mm = valid;
#pragma unroll
            for (int b = 0; b < 6; ++b) {
                unsigned long long bl = __ballot(((sv >> b) & 1) != 0);
                mm &= ((lane >> b) & 1) ? bl : ~bl;
            }
            cnt += (int)__popcll(mm);
        }
        // clamp to 10 (fits a nibble), butterfly-pack all 64 counts into pk[8]
        unsigned v = (cnt > 10) ? 10u : (unsigned)cnt;
        unsigned p;
        p = __shfl_xor(v, 1);  v = (lane & 1) ? (p | (v << 4))  : (v | (p << 4));
        p = __shfl_xor(v, 2);  v = (lane & 2) ? (p | (v << 8))  : (v | (p << 8));
        p = __shfl_xor(v, 4);  v = (lane & 4) ? (p | (v << 16)) : (v | (p << 16));
        unsigned q0, q1;
        p = __shfl_xor(v, 8);
        q0 = (lane & 8) ? p : v;  q1 = (lane & 8) ? v : p;
        unsigned r0 = __shfl_xor(q0, 16), r1 = __shfl_xor(q1, 16);
        unsigned s0, s1, s2, s3;
        if (lane & 16) { s0 = r0; s1 = r1; s2 = q0; s3 = q1; }
        else           { s0 = q0; s1 = q1; s2 = r0; s3 = r1; }
        unsigned t0 = __shfl_xor(s0, 32), t1 = __shfl_xor(s1, 32),
                 t2 = __shfl_xor(s2, 32), t3 = __shfl_xor(s3, 32);
        unsigned pk[8];
        if (lane & 32) { pk[0]=t0; pk[1]=t1; pk[2]=t2; pk[3]=t3; pk[4]=s0; pk[5]=s1; pk[6]=s2; pk[7]=s3; }
        else           { pk[0]=s0; pk[1]=s1; pk[2]=s2; pk[3]=s3; pk[4]=t0; pk[5]=t1; pk[6]=t2; pk[7]=t3; }

        int st_old = (int)st_in[node];
        double z = brec + (double)W_rec[(RG_S + st_old) * RG_S + lane];
#pragma unroll
        for (int k = 0; k < RG_S; ++k) {
            unsigned a = (pk[k >> 3] >> ((k & 7) * 4)) & 0xFu;  // all-static indexing
            z += (double)a * (double)wcol[k];                    // exact: int<=10 * f32 in f64
        }
        double y = (z - bnm) * bns + bnb;

        double best = y;
        int bi = lane;
#pragma unroll
        for (int off = 32; off; off >>= 1) {
            double ov = __shfl_xor(best, off);
            int oi = __shfl_xor(bi, off);
            if (ov > best || (ov == best && oi < bi)) { best = ov; bi = oi; }
        }
        if (lane == 0) st_out[node] = (unsigned char)bi;
    }
}

// ---------------------------------------------------------------------------
// Output MLP collapses to a 64x8 lookup table over the final state
// ---------------------------------------------------------------------------
__global__ void table_kernel(const float* __restrict__ Wo1, const float* __restrict__ bo1,
                             const float* __restrict__ g, const float* __restrict__ b,
                             const float* __restrict__ m, const float* __restrict__ v,
                             const float* __restrict__ Wo2, const float* __restrict__ bo2,
                             float* __restrict__ table) {
    int k = threadIdx.x;
    if (k >= RG_S) return;
    double h[RG_H];
#pragma unroll
    for (int j = 0; j < RG_H; ++j) {
        double z = (double)Wo1[k * RG_H + j] + (double)bo1[j];
        double y = (z - (double)m[j]) * ((double)g[j] / sqrt((double)v[j] + RG_BN_EPS)) +
                   (double)b[j];
        h[j] = y > 0.0 ? y : 0.0;
    }
#pragma unroll
    for (int o = 0; o < RG_OUT; ++o) {
        double acc = (double)bo2[o];
#pragma unroll
        for (int j = 0; j < RG_H; ++j) acc += h[j] * (double)Wo2[j * RG_OUT + o];
        table[k * RG_OUT + o] = (float)acc;
    }
}

__global__ void out_kernel(const unsigned char* __restrict__ st, const float* __restrict__ table,
                           float* __restrict__ out, int n) {
    int i = blockIdx.x * blockDim.x + threadIdx.x;
    if (i >= n) return;
    int s = (int)st[i];
    float4 a = ((const float4*)table)[s * 2];
    float4 b = ((const float4*)table)[s * 2 + 1];
    ((float4*)out)[(size_t)i * 2] = a;
    ((float4*)out)[(size_t)i * 2 + 1] = b;
}

// ---------------------------------------------------------------------------
extern "C" void kernel_launch(void* const* d_in, const int* in_sizes, int n_in,
                              void* d_out, int out_size, void* d_ws, size_t ws_size,
                              hipStream_t stream) {
    const float* x     = (const float*)d_in[0];
    const void*  ei    = d_in[1];
    const float* W_in  = (const float*)d_in[2];
    const float* b_in  = (const float*)d_in[3];
    const float* W_rec = (const float*)d_in[4];
    const float* b_rec = (const float*)d_in[5];
    const float* bn_g  = (const float*)d_in[6];
    const float* bn_b  = (const float*)d_in[7];
    const float* bn_m  = (const float*)d_in[8];
    const float* bn_v  = (const float*)d_in[9];
    const float* Wo1   = (const float*)d_in[10];
    const float* bo1   = (const float*)d_in[11];
    const float* bno_g = (const float*)d_in[12];
    const float* bno_b = (const float*)d_in[13];
    const float* bno_m = (const float*)d_in[14];
    const float* bno_v = (const float*)d_in[15];
    const float* Wo2   = (const float*)d_in[16];
    const float* bo2   = (const float*)d_in[17];

    int N = in_sizes[0] / RG_IN;
    int E = in_sizes[1] / 2;

    char* ws = (char*)d_ws;
    size_t off = 0;
    auto alloc = [&](size_t bytes) -> void* {
        void* p = ws + off;
        off = (off + bytes + 255) & ~(size_t)255;
        return p;
    };
    int nchunks = (N + 255) / 256;
    int*           flag    = (int*)alloc(sizeof(int));
    int*           deg     = (int*)alloc((size_t)N * sizeof(int));
    int*           row_off = (int*)alloc((size_t)(N + 1) * sizeof(int));
    int*           cursor  = (int*)alloc((size_t)N * sizeof(int));
    int*           adj     = (int*)alloc((size_t)E * sizeof(int));
    int*           srcs    = (int*)alloc((size_t)E * sizeof(int));
    int*           dsts    = (int*)alloc((size_t)E * sizeof(int));
    int*           bsum    = (int*)alloc((size_t)nchunks * sizeof(int));
    unsigned char* stA     = (unsigned char*)alloc((size_t)N);
    unsigned char* stB     = (unsigned char*)alloc((size_t)N);
    float*         table   = (float*)alloc(RG_S * RG_OUT * sizeof(float));

    hipMemsetAsync(deg, 0, (size_t)N * sizeof(int), stream);
    detect_i64_kernel<<<1, 64, 0, stream>>>((const unsigned int*)ei, flag);

    compact_kernel<<<2048, 256, 0, stream>>>(ei, flag, srcs, dsts, E);
    deg2_kernel<<<4096, 256, 0, stream>>>(dsts, deg, E, N);
    scanA_kernel<<<nchunks, 256, 0, stream>>>(deg, bsum, N);
    scanB_kernel<<<1, 512, 0, stream>>>(bsum, row_off, nchunks, N);
    scanC_kernel<<<nchunks, 256, 0, stream>>>(deg, bsum, row_off, cursor, N);
    fill2_kernel<<<4096, 256, 0, stream>>>(srcs, dsts, cursor, adj, E, N);

    input_kernel<<<1280, 256, 0, stream>>>(x, W_in, b_in, stA, N);

    unsigned char* sin = stA;
    unsigned char* sout = stB;
    for (int it = 0; it < RG_ITERS; ++it) {
        iter_kernel<<<1024, 256, 0, stream>>>(row_off, adj, sin, sout, W_rec, b_rec, bn_g, bn_b,
                                              bn_m, bn_v, N);
        unsigned char* t = sin; sin = sout; sout = t;
    }

    table_kernel<<<1, 64, 0, stream>>>(Wo1, bo1, bno_g, bno_b, bno_m, bno_v, Wo2, bo2, table);
    out_kernel<<<(N + 255) / 256, 256, 0, stream>>>(sin, table, (float*)d_out, N);
}